// Round 4
// baseline (1110.325 us; speedup 1.0000x reference)
//
#include <hip/hip_runtime.h>

// B=8, N=HW=4096, D=512, I=256, DO=512
// ws (ushort offsets):
//   featT  @0        [b][n][c] bf16 (k0a->k1); overlaid by out1 (k3->k4)
//   featV  @16777216 [b][mt=64][c=512][m=64] bf16 (k0a->k3)
//   phi_n  @33554432 [b][n][i] bf16 normalized (k1->k3)
//   theta_n@41943040
//   wb_phi @50331648 [i][c] bf16, wb_th @50462720, weightT @50593792 [d][c]

typedef short s8v __attribute__((ext_vector_type(8)));
typedef float f4v __attribute__((ext_vector_type(4)));

__device__ inline ushort f2bf(float x) {
  union { float f; unsigned u; } v; v.f = x;
  unsigned u = v.u + 0x7fff + ((v.u >> 16) & 1);
  return (ushort)(u >> 16);
}

// ---------- k0a: feat fp32 [b][c][m] -> featV blocked bf16 + featT bf16 ----
__global__ __launch_bounds__(256) void k0a(const float* __restrict__ feat,
                                           ushort* __restrict__ featT,
                                           ushort* __restrict__ featV) {
  int bid = blockIdx.x;
  int b = bid >> 9, cb = (bid >> 6) & 7, mt = bid & 63;
  int t = threadIdx.x;
  __shared__ ushort tile[64][72];

#pragma unroll
  for (int p = 0; p < 4; p++) {
    int ci = p * 16 + (t >> 4);
    int mi = (t & 15) * 4;
    float4 v = *(const float4*)&feat[((size_t)(b * 512 + cb * 64 + ci)) * 4096 + mt * 64 + mi];
    ushort4 u; u.x = f2bf(v.x); u.y = f2bf(v.y); u.z = f2bf(v.z); u.w = f2bf(v.w);
    *(ushort4*)&featV[((size_t)(b * 64 + mt) * 512 + cb * 64 + ci) * 64 + mi] = u;
    tile[ci][mi] = u.x; tile[ci][mi + 1] = u.y; tile[ci][mi + 2] = u.z; tile[ci][mi + 3] = u.w;
  }
  __syncthreads();
  int m = t >> 2, cs = (t & 3) * 16;
  ushort tmp[16];
#pragma unroll
  for (int j = 0; j < 16; j++) tmp[j] = tile[cs + j][m];
  ushort* dst = &featT[((size_t)(b * 4096 + mt * 64 + m)) * 512 + cb * 64 + cs];
  *(s8v*)dst = *(s8v*)&tmp[0];
  *(s8v*)(dst + 8) = *(s8v*)&tmp[8];
}

// ---------- k0b: cast phi_w / theta_w -> bf16 ------------------------------
__global__ __launch_bounds__(256) void k0b(const float* __restrict__ pw,
                                           const float* __restrict__ tw,
                                           ushort* __restrict__ wbp,
                                           ushort* __restrict__ wbt) {
  int bid = blockIdx.x;
  const float* src = (bid < 128) ? pw : tw;
  ushort* dst = (bid < 128) ? wbp : wbt;
  int idx = ((bid & 127) * 256 + threadIdx.x) * 4;
  float4 v = *(const float4*)&src[idx];
  ushort4 u; u.x = f2bf(v.x); u.y = f2bf(v.y); u.z = f2bf(v.z); u.w = f2bf(v.w);
  *(ushort4*)&dst[idx] = u;
}

// ---------- k0c: weight fp32 [c][d] -> weightT bf16 [d][c] -----------------
__global__ __launch_bounds__(256) void k0c(const float* __restrict__ w,
                                           ushort* __restrict__ wT) {
  int bid = blockIdx.x;
  int cb = bid >> 3, db = bid & 7;
  int t = threadIdx.x;
  __shared__ ushort tile[64][72];
#pragma unroll
  for (int p = 0; p < 4; p++) {
    int ci = p * 16 + (t >> 4);
    int di = (t & 15) * 4;
    float4 v = *(const float4*)&w[(size_t)(cb * 64 + ci) * 512 + db * 64 + di];
    tile[ci][di] = f2bf(v.x); tile[ci][di + 1] = f2bf(v.y);
    tile[ci][di + 2] = f2bf(v.z); tile[ci][di + 3] = f2bf(v.w);
  }
  __syncthreads();
  int d = t >> 2, cs = (t & 3) * 16;
  ushort tmp[16];
#pragma unroll
  for (int j = 0; j < 16; j++) tmp[j] = tile[cs + j][d];
  ushort* dst = &wT[(size_t)(db * 64 + d) * 512 + cb * 64 + cs];
  *(s8v*)dst = *(s8v*)&tmp[0];
  *(s8v*)(dst + 8) = *(s8v*)&tmp[8];
}

// ---------- k1: phi/theta MFMA GEMM + fused L2-normalize -> bf16 -----------
// grid 1024 = 8b x 2half x 64nt, block 256 (4 waves x 16 n-rows)
__global__ __launch_bounds__(256) void k1_gemm(
    const ushort* __restrict__ featT, const ushort* __restrict__ wbp,
    const ushort* __restrict__ wbt, ushort* __restrict__ phi_n,
    ushort* __restrict__ theta_n) {
  int bid = blockIdx.x;
  int b = bid & 7;
  int rest = bid >> 3;
  int half = rest & 1;
  int nt = rest >> 1;
  const ushort* wb = half ? wbt : wbp;
  ushort* dst = half ? theta_n : phi_n;
  int t = threadIdx.x;
  int lane = t & 63, w = t >> 6;
  int col = lane & 15, quad = lane >> 4;
  int n0 = nt * 64;

  const ushort* abase =
      featT + ((size_t)(b * 4096 + n0 + w * 16 + col)) * 512 + quad * 8;

  f4v acc[16];
#pragma unroll
  for (int i = 0; i < 16; i++) acc[i] = (f4v){0.f, 0.f, 0.f, 0.f};

#pragma unroll 2
  for (int kc = 0; kc < 16; kc++) {
    s8v a = *(const s8v*)(abase + kc * 32);
#pragma unroll
    for (int it = 0; it < 16; it++) {
      s8v bf = *(const s8v*)(wb + (size_t)(it * 16 + col) * 512 + kc * 32 + quad * 8);
      acc[it] = __builtin_amdgcn_mfma_f32_16x16x32_bf16(a, bf, acc[it], 0, 0, 0);
    }
  }
  float rinv[4];
#pragma unroll
  for (int reg = 0; reg < 4; reg++) {
    float ss = 0.f;
#pragma unroll
    for (int it = 0; it < 16; it++) ss += acc[it][reg] * acc[it][reg];
    ss += __shfl_xor(ss, 1); ss += __shfl_xor(ss, 2);
    ss += __shfl_xor(ss, 4); ss += __shfl_xor(ss, 8);
    rinv[reg] = rsqrtf(ss);
  }
#pragma unroll
  for (int it = 0; it < 16; it++) {
#pragma unroll
    for (int reg = 0; reg < 4; reg++) {
      dst[((size_t)(b * 4096 + n0 + w * 16 + quad * 4 + reg)) * 256 + it * 16 + col] =
          f2bf(acc[it][reg] * rinv[reg]);
    }
  }
}

// ---------- k3: MFMA flash attention, 1 barrier/iter, dbuf ks+ps -----------
// grid 512 = 8b(LSB) x 64qt, block 512 = 8 waves.
// QK: rg=w&3 (16 q-rows), mh=w>>2 (16-m half of 32-tile). PV: wave owns c [w*64,+64)
__global__ __launch_bounds__(512, 4) void k3_attn(
    const ushort* __restrict__ phi_n, const ushort* __restrict__ theta_n,
    const ushort* __restrict__ featV, ushort* __restrict__ out1) {
  int bid = blockIdx.x;
  int b = bid & 7;
  int n0 = (bid >> 3) << 6;
  int t = threadIdx.x;
  int lane = t & 63, w = t >> 6;
  int col = lane & 15, quad = lane >> 4;
  int rg = w & 3, mh = w >> 2;

  __shared__ __align__(16) ushort ks[2][32 * 256];  // swizzled: [row][chunk^(row&7)]
  __shared__ __align__(16) ushort ps[2][64 * 40];   // stride-40 rows (bank-clean)
  __shared__ float dred[2][64];

  // Q A-frags (persistent): A[n=rg*16+col][k=f*32+quad*8+j]
  s8v qf[8];
  {
    const ushort* qb = phi_n + ((size_t)(b * 4096 + n0 + rg * 16 + col)) * 256 + quad * 8;
#pragma unroll
    for (int f = 0; f < 8; f++) qf[f] = *(const s8v*)(qb + f * 32);
  }

  const ushort* thb = theta_n + (size_t)b * 4096 * 256;
  const ushort* vbb = featV + (size_t)b * 64 * 512 * 64;

  f4v acc[16];
#pragma unroll
  for (int i = 0; i < 16; i++) acc[i] = (f4v){0.f, 0.f, 0.f, 0.f};
  float denp[4] = {0.f, 0.f, 0.f, 0.f};

  int srow0 = w * 4 + (lane >> 5);  // this lane stages rows srow0, srow0+2
  int schunk = lane & 31;           // LDS chunk position within the row

  // pre-stage tile 0 into ks[0]: LDS(row,pos) = global(row, pos^(row&7))
#pragma unroll
  for (int u = 0; u < 2; u++) {
    int row = srow0 + u * 2;
    int gc = schunk ^ (row & 7);
    s8v val = *(const s8v*)(thb + (size_t)row * 256 + gc * 8);
    *(s8v*)(&ks[0][row * 256 + schunk * 8]) = val;
  }
  __syncthreads();

#pragma unroll 1
  for (int it = 0; it < 128; it++) {
    int cur = it & 1;
    const ushort* kcur = &ks[cur][0];
    ushort* pcur = &ps[cur][0];

    // 1. K-prefetch for it+1 (global -> regs)
    s8v kreg0, kreg1;
    if (it < 127) {
      size_t mb = (size_t)(it + 1) * 32;
      int r0 = srow0, r1 = srow0 + 2;
      kreg0 = *(const s8v*)(thb + (mb + r0) * 256 + ((schunk ^ (r0 & 7)) * 8));
      kreg1 = *(const s8v*)(thb + (mb + r1) * 256 + ((schunk ^ (r1 & 7)) * 8));
    }
    // 2. V-frags for this iter (blocked layout; consumed after the barrier)
    s8v vf[4];
    {
      const ushort* vb = vbb + ((size_t)(it >> 1)) * 512 * 64 + (it & 1) * 32 + quad * 8;
#pragma unroll
      for (int ct = 0; ct < 4; ct++)
        vf[ct] = *(const s8v*)(vb + (size_t)(w * 64 + ct * 16 + col) * 64);
    }
    // 3. QK: S[16 n (rg)][16 m (mh)]
    f4v sv = (f4v){0.f, 0.f, 0.f, 0.f};
    {
      int row = mh * 16 + col;
      const ushort* kb = kcur + row * 256;
#pragma unroll
      for (int kk = 0; kk < 8; kk++) {
        int pos = ((kk * 4 + quad) ^ (col & 7)) * 8;
        s8v bfrag = *(const s8v*)(kb + pos);
        sv = __builtin_amdgcn_mfma_f32_16x16x32_bf16(qf[kk], bfrag, sv, 0, 0, 0);
      }
    }
    // 4. exp (cos in [-1,1]: no max), den accum, P -> ps[cur]
#pragma unroll
    for (int r = 0; r < 4; r++) {
      float p = __expf(sv[r]);
      denp[r] += p;
      int n = rg * 16 + quad * 4 + r;
      pcur[n * 40 + mh * 16 + col] = f2bf(p);
    }
    // 5. write prefetched K-tile into other buffer
    if (it < 127) {
      ushort* kn = &ks[cur ^ 1][0];
      *(s8v*)(kn + srow0 * 256 + schunk * 8) = kreg0;
      *(s8v*)(kn + (srow0 + 2) * 256 + schunk * 8) = kreg1;
    }
    __syncthreads();  // the ONE barrier: ps[cur] ready, ks[next] ready
    // 6. PV: A = P rows (all 64 n), B = vf (this wave's 64-c range), k=32
#pragma unroll
    for (int rs = 0; rs < 4; rs++) {
      s8v pf = *(const s8v*)(pcur + (rs * 16 + col) * 40 + quad * 8);
#pragma unroll
      for (int ct = 0; ct < 4; ct++)
        acc[rs * 4 + ct] =
            __builtin_amdgcn_mfma_f32_16x16x32_bf16(pf, vf[ct], acc[rs * 4 + ct], 0, 0, 0);
    }
  }

  // denominator: reduce over col-group (m within half), then across halves
#pragma unroll
  for (int r = 0; r < 4; r++) {
    float d = denp[r];
    d += __shfl_xor(d, 1); d += __shfl_xor(d, 2);
    d += __shfl_xor(d, 4); d += __shfl_xor(d, 8);
    denp[r] = d;
  }
  if (col == 0) {
#pragma unroll
    for (int r = 0; r < 4; r++) dred[mh][rg * 16 + quad * 4 + r] = denp[r];
  }
  __syncthreads();
  if (t < 64) dred[0][t] = 1.0f / (dred[0][t] + dred[1][t]);
  __syncthreads();

  // store out1 bf16 [n][c]
#pragma unroll
  for (int rs = 0; rs < 4; rs++) {
#pragma unroll
    for (int ct = 0; ct < 4; ct++) {
#pragma unroll
      for (int reg = 0; reg < 4; reg++) {
        int n = rs * 16 + quad * 4 + reg;
        out1[((size_t)(b * 4096 + n0 + n)) * 512 + w * 64 + ct * 16 + col] =
            f2bf(acc[rs * 4 + ct][reg] * dred[0][n]);
      }
    }
  }
}

// ---------- k4: out = relu((out1 @ weight)^T) stored [b][d][n] fp32 --------
// grid 1024 = 8b x 8dt x 16nt, block 256 = 4 waves (wave -> 64-n slice)
__global__ __launch_bounds__(256) void k4_out(
    const ushort* __restrict__ out1, const ushort* __restrict__ wT,
    float* __restrict__ out) {
  int bid = blockIdx.x;
  int b = bid & 7;
  int rest = bid >> 3;
  int dt = rest & 7;
  int nt = rest >> 3;
  int t = threadIdx.x;
  int lane = t & 63, w = t >> 6;
  int col = lane & 15, quad = lane >> 4;
  int d0 = dt * 64;
  int n0 = nt * 256 + w * 64;

  f4v acc[16];
#pragma unroll
  for (int i = 0; i < 16; i++) acc[i] = (f4v){0.f, 0.f, 0.f, 0.f};

#pragma unroll 2
  for (int kc = 0; kc < 16; kc++) {
    s8v af[4], bf[4];
#pragma unroll
    for (int rs = 0; rs < 4; rs++)
      af[rs] = *(const s8v*)(wT + (size_t)(d0 + rs * 16 + col) * 512 + kc * 32 + quad * 8);
#pragma unroll
    for (int ct = 0; ct < 4; ct++)
      bf[ct] = *(const s8v*)(out1 + ((size_t)(b * 4096 + n0 + ct * 16 + col)) * 512 +
                             kc * 32 + quad * 8);
#pragma unroll
    for (int rs = 0; rs < 4; rs++)
#pragma unroll
      for (int ct = 0; ct < 4; ct++)
        acc[rs * 4 + ct] =
            __builtin_amdgcn_mfma_f32_16x16x32_bf16(af[rs], bf[ct], acc[rs * 4 + ct], 0, 0, 0);
  }
#pragma unroll
  for (int rs = 0; rs < 4; rs++) {
#pragma unroll
    for (int ct = 0; ct < 4; ct++) {
#pragma unroll
      for (int reg = 0; reg < 4; reg++) {
        int d = d0 + rs * 16 + quad * 4 + reg;
        int n = n0 + ct * 16 + col;
        out[((size_t)(b * 512 + d)) * 4096 + n] = fmaxf(acc[rs * 4 + ct][reg], 0.f);
      }
    }
  }
}

extern "C" void kernel_launch(void* const* d_in, const int* in_sizes, int n_in,
                              void* d_out, int out_size, void* d_ws, size_t ws_size,
                              hipStream_t stream) {
  const float* feat    = (const float*)d_in[0];
  const float* phi_w   = (const float*)d_in[1];
  const float* theta_w = (const float*)d_in[2];
  const float* weight  = (const float*)d_in[3];
  float* out = (float*)d_out;

  ushort* wsu = (ushort*)d_ws;
  ushort* featT   = wsu;                    // dead after k1 -> reused as out1
  ushort* featV   = wsu + 16777216;
  ushort* phi_n   = wsu + 33554432;
  ushort* theta_n = wsu + 41943040;
  ushort* wbp     = wsu + 50331648;
  ushort* wbt     = wsu + 50462720;
  ushort* weightT = wsu + 50593792;
  ushort* out1    = wsu;                    // overlays featT

  k0a<<<dim3(4096), dim3(256), 0, stream>>>(feat, featT, featV);
  k0b<<<dim3(256), dim3(256), 0, stream>>>(phi_w, theta_w, wbp, wbt);
  k0c<<<dim3(64), dim3(256), 0, stream>>>(weight, weightT);
  k1_gemm<<<dim3(1024), dim3(256), 0, stream>>>(featT, wbp, wbt, phi_n, theta_n);
  k3_attn<<<dim3(512), dim3(512), 0, stream>>>(phi_n, theta_n, featV, out1);
  k4_out<<<dim3(1024), dim3(256), 0, stream>>>(out1, weightT, out);
}